// Round 11
// baseline (209.936 us; speedup 1.0000x reference)
//
#include <hip/hip_runtime.h>
#include <math.h>

#define B_    2
#define S_    1024
#define HID_  2048
#define NH_   16
#define NKV_  4
#define HD_   128
#define GROUPS (NH_ / NKV_)
#define SCALE_ 0.08838834764831845f   // 1/sqrt(128)

#define NZ_   2                       // Q split-K factor
#define QPSZ  4194304                 // one Q partial (2048*2048)
#define KPSZ  1048576                 // K/V final buffer (512*2048)

typedef _Float16 f16x8 __attribute__((ext_vector_type(8)));
typedef _Float16 f16x4 __attribute__((ext_vector_type(4)));
typedef float    f32x4 __attribute__((ext_vector_type(4)));

// async global->LDS, 16B per lane; LDS dest = wave-uniform base + lane*16
__device__ __forceinline__ void async_copy16(const void* g, void* l) {
    __builtin_amdgcn_global_load_lds(
        (const __attribute__((address_space(1))) void*)g,
        (__attribute__((address_space(3))) void*)l, 16, 0, 0);
}

// DPP quad_perm(1,0,3,2): swap adjacent lane pairs. VALU op, no LDS pipe.
__device__ __forceinline__ int dpp_swap1(int x) {
    return __builtin_amdgcn_update_dpp(0, x, 0xB1, 0xF, 0xF, true);
}

// ---------------------------------------------------------------------------
// fused f32 -> f16 cast over 5 tensors (one launch for all inputs)
// ---------------------------------------------------------------------------
__global__ __launch_bounds__(256) void cast5_f16(
    const float4* __restrict__ s0, ushort4* __restrict__ d0, int n0,
    const float4* __restrict__ s1, ushort4* __restrict__ d1, int n1,
    const float4* __restrict__ s2, ushort4* __restrict__ d2, int n2,
    const float4* __restrict__ s3, ushort4* __restrict__ d3, int n3,
    const float4* __restrict__ s4, ushort4* __restrict__ d4, int n4)
{
    int i = blockIdx.x * 256 + threadIdx.x;
    const float4* s; ushort4* d; int idx;
    if (i < n0)                          { s = s0; d = d0; idx = i; }
    else if (i < n0 + n1)                { s = s1; d = d1; idx = i - n0; }
    else if (i < n0 + n1 + n2)           { s = s2; d = d2; idx = i - n0 - n1; }
    else if (i < n0 + n1 + n2 + n3)      { s = s3; d = d3; idx = i - n0 - n1 - n2; }
    else if (i < n0 + n1 + n2 + n3 + n4) { s = s4; d = d4; idx = i - n0 - n1 - n2 - n3; }
    else return;
    float4 v = s[idx];
    _Float16 a = (_Float16)v.x, b = (_Float16)v.y,
             c = (_Float16)v.z, e = (_Float16)v.w;
    ushort4 o;
    o.x = *(unsigned short*)&a; o.y = *(unsigned short*)&b;
    o.z = *(unsigned short*)&c; o.w = *(unsigned short*)&e;
    d[idx] = o;
}

// ---------------------------------------------------------------------------
// Fused QKV GEMM. Grid (24, 16, 2). R11 split-K rebalance:
//  - Q blocks (bt<16): split-K=2 over z (32 steps) -> f16 partials, reduced
//    by stick_attn's fused Q path (each Q row consumed by exactly 1 block).
//  - K/V blocks (bt>=16): z=0 runs the FULL K=2048 (64 steps), z=1 exits.
//    Output is FINAL: V -> Vh directly (no rope needed, V pass eliminated),
//    K -> single pre-rope buffer (rope_k reads 1x, no partial reduce).
//  Work conserved (24576 block-steps); long K/V blocks dispatch first.
// Triple-buffer, ONE barrier per K-step; counted vmcnt(4); T2 swizzle.
// ---------------------------------------------------------------------------
__global__ __launch_bounds__(256) void qkv_gemm(
    const _Float16* __restrict__ A,
    const _Float16* __restrict__ Wq,
    const _Float16* __restrict__ Wk,
    const _Float16* __restrict__ Wv,
    _Float16* __restrict__ Qp,    // 2 x QPSZ (partials)
    _Float16* __restrict__ Kpre,  // KPSZ (final, pre-rope)
    _Float16* __restrict__ Vh)    // KPSZ (final)
{
    // 3 buffers: buf d at d*16384; A at +0, W at +8192 (bytes)
    __shared__ __align__(16) unsigned char smem[49152];

    const int tid  = threadIdx.x;
    const int lane = tid & 63, wave = tid >> 6;
    const int wr = (wave >> 1) * 64, wc = (wave & 1) * 64;
    const int bm = blockIdx.y * 128;
    const int bt = blockIdx.x;
    const int z  = blockIdx.z;

    const _Float16* Wsel;
    _Float16* Csel;
    int nrow0, heads, kbase, nsteps;
    if (bt < 16) {
        Wsel = Wq; Csel = Qp + (size_t)z * QPSZ;
        nrow0 = bt * 128; heads = NH_;
        kbase = z * (HID_ / NZ_); nsteps = HID_ / NZ_ / 32;   // 32
    } else {
        if (z) return;                      // K/V handled entirely by z=0
        if (bt < 20) { Wsel = Wk; Csel = Kpre; nrow0 = (bt - 16) * 128; }
        else         { Wsel = Wv; Csel = Vh;   nrow0 = (bt - 20) * 128; }
        heads = NKV_; kbase = 0; nsteps = HID_ / 32;          // 64
    }

    const int srow = 32 * wave + (lane >> 2);
    // inverse-swizzled global source chunk (T2 both-sides)
    const int scol = (((lane & 3) ^ ((lane >> 3) & 3))) * 8;
    const _Float16* Ag = A    + (size_t)(bm + srow)    * HID_ + kbase + scol;
    const _Float16* Wg = Wsel + (size_t)(nrow0 + srow) * HID_ + kbase + scol;

    // wave-uniform staging bases; HW adds lane*16B (linear dest)
    const unsigned aoff = (unsigned)(wave * 2048);

    f32x4 acc[4][4];
    const f32x4 fz = {0.f, 0.f, 0.f, 0.f};
#pragma unroll
    for (int i = 0; i < 4; i++)
#pragma unroll
        for (int j = 0; j < 4; j++) acc[i][j] = fz;

    const int ml = lane & 15, kg = lane >> 4;
    const int kgx = kg ^ ((ml >> 1) & 3);   // swizzled read chunk (per-lane const)

#define QKV_STAGE(d, k0) do {                                                 \
        _Float16* la_ = (_Float16*)(smem + (d) * 16384 + aoff);               \
        _Float16* lw_ = (_Float16*)(smem + (d) * 16384 + 8192 + aoff);        \
        async_copy16(Ag + (k0), la_);                                         \
        async_copy16(Ag + (k0) + (size_t)16 * HID_, la_ + 16 * 32);           \
        async_copy16(Wg + (k0), lw_);                                         \
        async_copy16(Wg + (k0) + (size_t)16 * HID_, lw_ + 16 * 32);           \
    } while (0)

#define QKV_COMPUTE(d) do {                                                   \
        const _Float16* tA = (const _Float16*)(smem + (d) * 16384);           \
        const _Float16* tW = (const _Float16*)(smem + (d) * 16384 + 8192);    \
        f16x8 a[4], b[4];                                                     \
        _Pragma("unroll")                                                     \
        for (int mi = 0; mi < 4; mi++)                                        \
            a[mi] = *(const f16x8*)&tA[(wr + mi * 16 + ml) * 32 + kgx * 8];   \
        _Pragma("unroll")                                                     \
        for (int ni = 0; ni < 4; ni++)                                        \
            b[ni] = *(const f16x8*)&tW[(wc + ni * 16 + ml) * 32 + kgx * 8];   \
        _Pragma("unroll")                                                     \
        for (int mi = 0; mi < 4; mi++)                                        \
            _Pragma("unroll")                                                 \
            for (int ni = 0; ni < 4; ni++)                                    \
                acc[mi][ni] = __builtin_amdgcn_mfma_f32_16x16x32_f16(         \
                    a[mi], b[ni], acc[mi][ni], 0, 0, 0);                      \
    } while (0)

    QKV_STAGE(0, 0);
    int cbuf = 0;
    for (int t = 0; t < nsteps - 1; t++) {
        int nbuf = (cbuf == 2) ? 0 : cbuf + 1;
        QKV_STAGE(nbuf, (t + 1) * 32);    // 4 loads issued, stay in flight
        // retire only the 4 OLDEST loads (= buffer cbuf, staged last iter)
        asm volatile("s_waitcnt vmcnt(4)" ::: "memory");
        __builtin_amdgcn_s_barrier();
        __builtin_amdgcn_sched_barrier(0);

        QKV_COMPUTE(cbuf);                // no trailing barrier (3-buf safety)
        cbuf = nbuf;
    }
    // peeled last tile
    asm volatile("s_waitcnt vmcnt(0)" ::: "memory");
    __builtin_amdgcn_s_barrier();
    __builtin_amdgcn_sched_barrier(0);
    QKV_COMPUTE(cbuf);
#undef QKV_STAGE
#undef QKV_COMPUTE

#pragma unroll
    for (int mi = 0; mi < 4; mi++) {
#pragma unroll
        for (int ni = 0; ni < 4; ni++) {
#pragma unroll
            for (int r = 0; r < 4; r++) {
                int m = bm + wr + mi * 16 + kg * 4 + r;
                int n = nrow0 + wc + ni * 16 + ml;
                int hh = n >> 7, d2 = n & 127;
                int b_ = m >> 10, s = m & 1023;
                size_t idx = (((size_t)(b_ * heads + hh)) * S_ + s) * HD_ + d2;
                Csel[idx] = (_Float16)acc[mi][ni][r];
            }
        }
    }
}

// ---------------------------------------------------------------------------
// Output GEMM, in-block split-K=2, 512 threads, grid (16,16) = 1 block/CU.
// Triple-buffer, one barrier per K-step; counted vmcnt(4); T2 swizzle.
// (R9 structure — converged; not touched.)
// ---------------------------------------------------------------------------
__global__ __launch_bounds__(512) void out_gemm(
    const _Float16* __restrict__ A,
    const _Float16* __restrict__ W,
    float* __restrict__ Cout)
{
    // 3 buffers: buf d at d*32768; A(kh) at +kh*8192, W(kh) at +16384+kh*8192
    __shared__ __align__(16) unsigned char smem[98304];

    const int tid  = threadIdx.x;
    const int lane = tid & 63, wave = tid >> 6;
    const int kh = wave >> 2;               // K-half this wave owns
    const int wv = wave & 3;                // tile-wave within half
    const int wr = (wv >> 1) * 64, wc = (wv & 1) * 64;
    const int bm = blockIdx.y * 128, bn = blockIdx.x * 128;
    const int kbase = kh * (HID_ / 2);

    const int srow = 32 * wv + (lane >> 2);
    const int scol = (((lane & 3) ^ ((lane >> 3) & 3))) * 8;   // inverse-swz src
    const _Float16* Ag = A + (size_t)(bm + srow) * HID_ + kbase + scol;
    const _Float16* Wg = W + (size_t)(bn + srow) * HID_ + kbase + scol;

    const unsigned aoff = (unsigned)(kh * 8192 + 32 * wv * 64);
    const unsigned woff = (unsigned)(16384 + kh * 8192 + 32 * wv * 64);

    f32x4 acc[4][4];
    const f32x4 fz = {0.f, 0.f, 0.f, 0.f};
#pragma unroll
    for (int i = 0; i < 4; i++)
#pragma unroll
        for (int j = 0; j < 4; j++) acc[i][j] = fz;

    const int ml = lane & 15, kg = lane >> 4;
    const int kgx = kg ^ ((ml >> 1) & 3);   // swizzled read chunk

#define OG_STAGE(d, k0) do {                                                  \
        _Float16* la_ = (_Float16*)(smem + (d) * 32768 + aoff);               \
        _Float16* lw_ = (_Float16*)(smem + (d) * 32768 + woff);               \
        async_copy16(Ag + (k0), la_);                                         \
        async_copy16(Ag + (k0) + (size_t)16 * HID_, la_ + 16 * 32);           \
        async_copy16(Wg + (k0), lw_);                                         \
        async_copy16(Wg + (k0) + (size_t)16 * HID_, lw_ + 16 * 32);           \
    } while (0)

#define OG_COMPUTE(d) do {                                                    \
        const _Float16* tA = (const _Float16*)(smem + (d) * 32768 + kh * 8192);\
        const _Float16* tW = (const _Float16*)(smem + (d) * 32768 + 16384 + kh * 8192);\
        f16x8 a[4], b[4];                                                     \
        _Pragma("unroll")                                                     \
        for (int mi = 0; mi < 4; mi++)                                        \
            a[mi] = *(const f16x8*)&tA[(wr + mi * 16 + ml) * 32 + kgx * 8];   \
        _Pragma("unroll")                                                     \
        for (int ni = 0; ni < 4; ni++)                                        \
            b[ni] = *(const f16x8*)&tW[(wc + ni * 16 + ml) * 32 + kgx * 8];   \
        _Pragma("unroll")                                                     \
        for (int mi = 0; mi < 4; mi++)                                        \
            _Pragma("unroll")                                                 \
            for (int ni = 0; ni < 4; ni++)                                    \
                acc[mi][ni] = __builtin_amdgcn_mfma_f32_16x16x32_f16(         \
                    a[mi], b[ni], acc[mi][ni], 0, 0, 0);                      \
    } while (0)

    OG_STAGE(0, 0);
    int cbuf = 0;
    for (int t = 0; t < 31; t++) {
        int nbuf = (cbuf == 2) ? 0 : cbuf + 1;
        OG_STAGE(nbuf, (t + 1) * 32);    // 4 loads issued, stay in flight
        asm volatile("s_waitcnt vmcnt(4)" ::: "memory");
        __builtin_amdgcn_s_barrier();
        __builtin_amdgcn_sched_barrier(0);

        OG_COMPUTE(cbuf);                // no trailing barrier (3-buf safety)
        cbuf = nbuf;
    }
    asm volatile("s_waitcnt vmcnt(0)" ::: "memory");
    __builtin_amdgcn_s_barrier();
    __builtin_amdgcn_sched_barrier(0);
    OG_COMPUTE(cbuf);
#undef OG_STAGE
#undef OG_COMPUTE

    // cross-half reduce through LDS (aliases staging; stride 65 floats keeps
    // scalar f32 accesses conflict-free on the 32 banks)
    __syncthreads();                     // full drain before aliasing smem
    float* red = (float*)smem;
    float* rp  = red + ((size_t)(wv * 64 + lane)) * 65;
    if (kh == 1) {
#pragma unroll
        for (int mi = 0; mi < 4; mi++)
#pragma unroll
            for (int ni = 0; ni < 4; ni++)
#pragma unroll
                for (int r = 0; r < 4; r++)
                    rp[mi * 16 + ni * 4 + r] = acc[mi][ni][r];
    }
    __syncthreads();
    if (kh == 0) {
#pragma unroll
        for (int mi = 0; mi < 4; mi++)
#pragma unroll
            for (int ni = 0; ni < 4; ni++)
#pragma unroll
                for (int r = 0; r < 4; r++) {
                    float v = acc[mi][ni][r] + rp[mi * 16 + ni * 4 + r];
                    int m = bm + wr + mi * 16 + kg * 4 + r;
                    int n = bn + wc + ni * 16 + ml;
                    Cout[(size_t)m * HID_ + n] = v;
                }
    }
}

// ---------------------------------------------------------------------------
// R11: K-only rope+rms (V now written final by qkv; no partial reduce).
// 8192 rows; grid 2048 x 256.
// ---------------------------------------------------------------------------
__global__ __launch_bounds__(256) void rope_k(
    const _Float16* __restrict__ Kpre, const float* __restrict__ kw,
    _Float16* __restrict__ Kout)
{
    int row = blockIdx.x * 4 + (threadIdx.x >> 6);
    int lane = threadIdx.x & 63;

    _Float16* q = Kout + (size_t)row * HD_;
    int s = row & (S_ - 1);
    size_t base = (size_t)row * HD_;
    float x1 = (float)Kpre[base + lane];
    float x2 = (float)Kpre[base + lane + 64];

    float invf = __builtin_amdgcn_exp2f(-(float)lane * 0.2076205059304601f);
    float ang = (float)s * invf;
    float sn = __sinf(ang);
    float c  = __cosf(ang);

    float y1 = x1 * c - x2 * sn;
    float y2 = x1 * sn + x2 * c;

    float ss = y1 * y1 + y2 * y2;
#pragma unroll
    for (int off = 32; off > 0; off >>= 1) ss += __shfl_xor(ss, off);

    float scl = rsqrtf(ss * (1.0f / 128.0f) + 1e-6f);
    q[lane]      = (_Float16)(y1 * scl * kw[lane]);
    q[lane + 64] = (_Float16)(y2 * scl * kw[lane + 64]);
}

// ---------------------------------------------------------------------------
// MFMA stick-breaking attention with K/V register prefetch.
// Q path fused: reads both Qp split-K partials, applies RoPE + RMSNorm while
// the first K/V prefetch is in flight, writes Qs.
// BQ=BK=64, 512 threads (8 waves). T5 setprio around MFMA clusters.
// ---------------------------------------------------------------------------
#define QK_STR 136
#define VT_STR 72
#define SS_STR 68
#define AT_STR 72

__global__ __launch_bounds__(512) void stick_attn(
    const _Float16* __restrict__ Qp,   // 2 x QPSZ pre-rope partials
    const _Float16* __restrict__ K,
    const _Float16* __restrict__ V,
    const float* __restrict__ qwgt,
    _Float16* __restrict__ AO)
{
    __shared__ __align__(16) _Float16 Qs[64][QK_STR];
    __shared__ __align__(16) _Float16 Ks[64][QK_STR];
    __shared__ __align__(16) _Float16 Vt[128][VT_STR];
    __shared__ __align__(16) float    Ss[64][SS_STR];
    __shared__ __align__(16) _Float16 atts[64][AT_STR];
    __shared__ float paccs[64];

    const int bid = blockIdx.x;
    const int slot = bid & 255, phase = bid >> 8;
    const int hb = slot >> 3, iw = slot & 7;
    const int b = hb >> 4, h = hb & 15;
    const int qb = phase ? iw : 15 - iw;

    const int kvh = h / GROUPS;
    const int tid = threadIdx.x;
    const int lane = tid & 63, wave = tid >> 6;
    const int qw = wave >> 1;
    const int kh = wave & 1;
    const int ml = lane & 15, quad = lane >> 4;

    const _Float16* Kbase = K + ((size_t)(b * NKV_ + kvh) * S_) * HD_;
    const _Float16* Vbase = V + ((size_t)(b * NKV_ + kvh) * S_) * HD_;

    const f32x4 fz = {0.f, 0.f, 0.f, 0.f};

    const int qi0 = qb * 64;

    // K staging geometry: thread loads rows kr, kr+32 at col kc (8 f16)
    const int kr = tid >> 4, kc = (tid & 15) * 8;
    // V staging geometry: thread loads key=lane, d-range wave*16 .. +16
    const _Float16* Vrow = Vbase + (size_t)lane * HD_ + wave * 16;

    // prefetch first tile (kb = qb) — issued BEFORE Q-rope so the HBM
    // latency hides under the rope VALU work below
    f16x8 kA, kB, vA, vB;
    {
        const _Float16* kp = Kbase + (size_t)(qb * 64 + kr) * HD_ + kc;
        kA = *(const f16x8*)(kp);
        kB = *(const f16x8*)(kp + (size_t)32 * HD_);
        const _Float16* vp = Vrow + (size_t)(qb * 64) * HD_;
        vA = *(const f16x8*)(vp);
        vB = *(const f16x8*)(vp + 8);
    }

    // fused Q: split-K reduce + RoPE + RMSNorm -> Qs (8 rows per wave)
    {
        float invf = __builtin_amdgcn_exp2f(-(float)lane * 0.2076205059304601f);
        float w1 = qwgt[lane], w2 = qwgt[lane + 64];
        size_t qbase = ((size_t)(b * NH_ + h) * S_ + qi0 + wave * 8) * HD_;
#pragma unroll
        for (int r8 = 0; r8 < 8; r8++) {
            int row = wave * 8 + r8;
            size_t base = qbase + (size_t)r8 * HD_;
            float x1 = (float)Qp[base + lane]
                     + (float)Qp[QPSZ + base + lane];
            float x2 = (float)Qp[base + lane + 64]
                     + (float)Qp[QPSZ + base + lane + 64];
            float ang = (float)(qi0 + row) * invf;
            float sn = __sinf(ang);
            float c  = __cosf(ang);
            float y1 = x1 * c - x2 * sn;
            float y2 = x1 * sn + x2 * c;
            float ss = y1 * y1 + y2 * y2;
#pragma unroll
            for (int off = 32; off > 0; off >>= 1) ss += __shfl_xor(ss, off);
            float scl = rsqrtf(ss * (1.0f / 128.0f) + 1e-6f);
            Qs[row][lane]      = (_Float16)(y1 * scl * w1);
            Qs[row][lane + 64] = (_Float16)(y2 * scl * w2);
        }
    }
    if (tid < 64) paccs[tid] = 1.f;
    __syncthreads();

    f16x8 aq[4];
#pragma unroll
    for (int ks = 0; ks < 4; ks++)
        aq[ks] = *(const f16x8*)&Qs[qw * 16 + ml][ks * 32 + quad * 8];

    f32x4 accO[4] = {fz, fz, fz, fz};

    for (int kb = qb; kb >= 0; --kb) {
        __syncthreads();   // prev PV/scan reads of Ks/Vt/Ss/atts done

        // stage prefetched K from registers (b128 writes)
        *(f16x8*)&Ks[kr][kc]      = kA;
        *(f16x8*)&Ks[kr + 32][kc] = kB;

        // stage prefetched V transposed: DPP pair-exchange + packed b32 writes
        {
            int4 i0 = *(int4*)&vA, i1 = *(int4*)&vB;
            int4 p0, p1;
            p0.x = dpp_swap1(i0.x); p0.y = dpp_swap1(i0.y);
            p0.z = dpp_swap1(i0.z); p0.w = dpp_swap1(i0.w);
            p1.x = dpp_swap1(i1.x); p1.y = dpp_swap1(i1.y);
            p1.z = dpp_swap1(i1.z); p1.w = dpp_swap1(i1.w);
            bool ev = !(lane & 1);
            int4 al = ev ? i0 : p1;   // low halves: key 2k
            int4 bh = ev ? p0 : i1;   // high halves: key 2k+1
            int r0w = wave * 16 + (ev ? 0 : 8);
            int colk = lane & ~1;
            int ac[4] = {al.x, al.y, al.z, al.w};
            int bc[4] = {bh.x, bh.y, bh.z, bh.w};
#pragma unroll
            for (int i = 0; i < 8; i++) {
                int c = i >> 1;
                unsigned pack = (i & 1)
                    ? (((unsigned)ac[c] >> 16) | ((unsigned)bc[c] & 0xffff0000u))
                    : (((unsigned)ac[c] & 0xffffu) | ((unsigned)bc[c] << 16));
                *(unsigned*)&Vt[r0w + i][colk] = pack;
            }
        }
        __syncthreads();

        // issue prefetch for next tile — consumed at next staging phase,
        // covered by the QK+scan+PV compute below
        if (kb > 0) {
            const _Float16* kp = Kbase + (size_t)((kb - 1) * 64 + kr) * HD_ + kc;
            kA = *(const f16x8*)(kp);
            kB = *(const f16x8*)(kp + (size_t)32 * HD_);
            const _Float16* vp = Vrow + (size_t)((kb - 1) * 64) * HD_;
            vA = *(const f16x8*)(vp);
            vB = *(const f16x8*)(vp + 8);
        }

        // QK^T -> Ss (scaled)
        f32x4 accS[2] = {fz, fz};
        __builtin_amdgcn_s_setprio(1);
#pragma unroll
        for (int ks = 0; ks < 4; ks++) {
#pragma unroll
            for (int ni = 0; ni < 2; ni++) {
                f16x8 bf = *(const f16x8*)
                    &Ks[kh * 32 + ni * 16 + ml][ks * 32 + quad * 8];
                accS[ni] = __builtin_amdgcn_mfma_f32_16x16x32_f16(
                    aq[ks], bf, accS[ni], 0, 0, 0);
            }
        }
        __builtin_amdgcn_s_setprio(0);
#pragma unroll
        for (int ni = 0; ni < 2; ni++)
#pragma unroll
            for (int r = 0; r < 4; r++)
                Ss[qw * 16 + quad * 4 + r][kh * 32 + ni * 16 + ml] =
                    accS[ni][r] * SCALE_;
        __syncthreads();

        // sigmoid-domain scan: om = sig(-L) exact, s = 1-om, suffix products
        {
            int q = tid >> 3, seg = tid & 7;
            int qg = qi0 + q;
            int j0 = kb * 64 + seg * 8;
            float4 s0 = *(float4*)&Ss[q][seg * 8];
            float4 s1 = *(float4*)&Ss[q][seg * 8 + 4];
            float L[8] = {s0.x, s0.y, s0.z, s0.w, s1.x, s1.y, s1.z, s1.w};
            float sv[8], om[8];
#pragma unroll
            for (int i = 0; i < 8; i++) {
                float u = __expf(L[i]);
                float o = __builtin_amdgcn_rcpf(1.f + u);
                bool valid = (j0 + i < qg);
                om[i] = valid ? o : 1.f;
                sv[i] = valid ? (1.f - o) : 0.f;
            }
            float suf = 1.f, lo[8];
#pragma unroll
            for (int i = 7; i >= 0; --i) {
                lo[i] = suf; suf *= om[i];
            }
            float x = suf;
#pragma unroll
            for (int off = 1; off < 8; off <<= 1) {
                float y = __shfl_down(x, off);
                if (seg + off < 8) x *= y;
            }
            float bx = __shfl_down(x, 1);
            float base = (seg == 7) ? 1.f : bx;
            float paccq = paccs[q];
            float pb = base * paccq;
            f16x8 av;
#pragma unroll
            for (int i = 0; i < 8; i++)
                av[i] = (_Float16)(sv[i] * lo[i] * pb);
            *(f16x8*)&atts[q][seg * 8] = av;
            if (seg == 0) paccs[q] = paccq * x;
        }
        __syncthreads();

        // PV
        __builtin_amdgcn_s_setprio(1);
#pragma unroll
        for (int ks = 0; ks < 2; ks++) {
            f16x8 ap = *(const f16x8*)&atts[qw * 16 + ml][ks * 32 + quad * 8];
#pragma unroll
            for (int ni = 0; ni < 4; ni++) {
                f16x8 bv = *(const f16x8*)
                    &Vt[kh * 64 + ni * 16 + ml][ks * 32 + quad * 8];
                accO[ni] = __builtin_amdgcn_mfma_f32_16x16x32_f16(
                    ap, bv, accO[ni], 0, 0, 0);
            }
        }
        __builtin_amdgcn_s_setprio(0);
    }

#pragma unroll
    for (int ni = 0; ni < 4; ni++) {
#pragma unroll
        for (int r = 0; r < 4; r++) {
            int qg = qi0 + qw * 16 + quad * 4 + r;
            int d = kh * 64 + ni * 16 + ml;
            AO[((size_t)(b * S_ + qg) * NH_ + h) * HD_ + d] =
                (_Float16)accO[ni][r];
        }
    }
}

// ---------------------------------------------------------------------------
extern "C" void kernel_launch(void* const* d_in, const int* in_sizes, int n_in,
                              void* d_out, int out_size, void* d_ws, size_t ws_size,
                              hipStream_t stream)
{
    const float* hs = (const float*)d_in[0];
    const float* Wq = (const float*)d_in[1];
    const float* Wk = (const float*)d_in[2];
    const float* Wv = (const float*)d_in[3];
    const float* Wo = (const float*)d_in[4];
    const float* qw = (const float*)d_in[5];
    const float* kw = (const float*)d_in[6];
    float* out = (float*)d_out;

    // f16 workspace layout
    _Float16* Qp   = (_Float16*)d_ws;          // 2 x QPSZ (partials)
    _Float16* Kpre = Qp + (size_t)NZ_ * QPSZ;  // KPSZ (final pre-rope K)
    _Float16* Vh   = Kpre + KPSZ;              // KPSZ (final V)
    _Float16* hsh  = Vh + KPSZ;
    _Float16* Wqh  = hsh + 4194304;
    _Float16* Wkh  = Wqh + 4194304;
    _Float16* Wvh  = Wkh + 1048576;
    _Float16* Woh  = Wvh + 1048576;            // 4,194,304
    _Float16* Kh   = Woh + 4194304;            // post-rope K
    // stream-ordered alias
    _Float16* AOh = hsh;   // attention out, after qkv consumed hs

    dim3 blk(256);

    // one launch: cast hs | Wq | Wk | Wv | Wo to f16
    cast5_f16<<<14336, blk, 0, stream>>>(
        (const float4*)hs, (ushort4*)hsh, 1048576,
        (const float4*)Wq, (ushort4*)Wqh, 1048576,
        (const float4*)Wk, (ushort4*)Wkh, 262144,
        (const float4*)Wv, (ushort4*)Wvh, 262144,
        (const float4*)Wo, (ushort4*)Woh, 1048576);

    // fused QKV projection: Q split-K=2 partials; K/V full-K final outputs
    qkv_gemm<<<dim3(24, 16, NZ_), blk, 0, stream>>>(hsh, Wqh, Wkh, Wvh,
                                                    Qp, Kpre, Vh);

    // K rope+rms only (V final from qkv; Q fused in stick_attn)
    rope_k<<<dim3(8192 / 4), blk, 0, stream>>>(Kpre, kw, Kh);

    // stick-breaking attention (fused Q reduce+rope+rms) -> f16 (b,s,h,d)
    stick_attn<<<dim3(512), dim3(512), 0, stream>>>(Qp, Kh, Vh, qw, AOh);

    // output projection, triple-buffer 1-barrier pipeline -> f32 out
    out_gemm<<<dim3(16, 16), dim3(512), 0, stream>>>(AOh, Woh, out);
}

// Round 12
// 203.420 us; speedup vs baseline: 1.0320x; 1.0320x over previous
//
#include <hip/hip_runtime.h>
#include <math.h>

#define B_    2
#define S_    1024
#define HID_  2048
#define NH_   16
#define NKV_  4
#define HD_   128
#define GROUPS (NH_ / NKV_)
#define SCALE_ 0.08838834764831845f   // 1/sqrt(128)

#define NZ_   2                       // qkv split-K factor
#define QPSZ  4194304                 // one Q partial (2048*2048)
#define KPSZ  1048576                 // one K/V partial (512*2048)

typedef _Float16 f16x8 __attribute__((ext_vector_type(8)));
typedef _Float16 f16x4 __attribute__((ext_vector_type(4)));
typedef float    f32x4 __attribute__((ext_vector_type(4)));

// async global->LDS, 16B per lane; LDS dest = wave-uniform base + lane*16
__device__ __forceinline__ void async_copy16(const void* g, void* l) {
    __builtin_amdgcn_global_load_lds(
        (const __attribute__((address_space(1))) void*)g,
        (__attribute__((address_space(3))) void*)l, 16, 0, 0);
}

// DPP quad_perm(1,0,3,2): swap adjacent lane pairs. VALU op, no LDS pipe.
__device__ __forceinline__ int dpp_swap1(int x) {
    return __builtin_amdgcn_update_dpp(0, x, 0xB1, 0xF, 0xF, true);
}

// ---------------------------------------------------------------------------
// fused f32 -> f16 cast over 5 tensors (one launch for all inputs)
// ---------------------------------------------------------------------------
__global__ __launch_bounds__(256) void cast5_f16(
    const float4* __restrict__ s0, ushort4* __restrict__ d0, int n0,
    const float4* __restrict__ s1, ushort4* __restrict__ d1, int n1,
    const float4* __restrict__ s2, ushort4* __restrict__ d2, int n2,
    const float4* __restrict__ s3, ushort4* __restrict__ d3, int n3,
    const float4* __restrict__ s4, ushort4* __restrict__ d4, int n4)
{
    int i = blockIdx.x * 256 + threadIdx.x;
    const float4* s; ushort4* d; int idx;
    if (i < n0)                          { s = s0; d = d0; idx = i; }
    else if (i < n0 + n1)                { s = s1; d = d1; idx = i - n0; }
    else if (i < n0 + n1 + n2)           { s = s2; d = d2; idx = i - n0 - n1; }
    else if (i < n0 + n1 + n2 + n3)      { s = s3; d = d3; idx = i - n0 - n1 - n2; }
    else if (i < n0 + n1 + n2 + n3 + n4) { s = s4; d = d4; idx = i - n0 - n1 - n2 - n3; }
    else return;
    float4 v = s[idx];
    _Float16 a = (_Float16)v.x, b = (_Float16)v.y,
             c = (_Float16)v.z, e = (_Float16)v.w;
    ushort4 o;
    o.x = *(unsigned short*)&a; o.y = *(unsigned short*)&b;
    o.z = *(unsigned short*)&c; o.w = *(unsigned short*)&e;
    d[idx] = o;
}

// ---------------------------------------------------------------------------
// Fused QKV GEMM, split-K=2. Grid (24, 16, 2) = 768 blocks = 3 blocks/CU.
// Triple-buffer, ONE barrier per K-step; counted vmcnt(4); T2 swizzle.
// (R9/R10 structure — converged at ~614 TF, above the m102 reference curve
// for this problem size. R11's full-K K/V rebalance regressed: 2x-length
// straggler blocks + doubled A re-fetch. Uniform block length wins.)
// ---------------------------------------------------------------------------
__global__ __launch_bounds__(256) void qkv_gemm(
    const _Float16* __restrict__ A,
    const _Float16* __restrict__ Wq,
    const _Float16* __restrict__ Wk,
    const _Float16* __restrict__ Wv,
    _Float16* __restrict__ Qp,   // 2 x QPSZ
    _Float16* __restrict__ Kp,   // 2 x KPSZ
    _Float16* __restrict__ Vp)   // 2 x KPSZ
{
    // 3 buffers: buf d at d*16384; A at +0, W at +8192 (bytes)
    __shared__ __align__(16) unsigned char smem[49152];

    const int tid  = threadIdx.x;
    const int lane = tid & 63, wave = tid >> 6;
    const int wr = (wave >> 1) * 64, wc = (wave & 1) * 64;
    const int bm = blockIdx.y * 128;
    const int bt = blockIdx.x;
    const int z  = blockIdx.z;
    const int kbase = z * (HID_ / NZ_);

    const _Float16* Wsel;
    _Float16* Csel;
    int nrow0, heads;
    if (bt < 16)      { Wsel = Wq; Csel = Qp + (size_t)z * QPSZ; nrow0 = bt * 128;        heads = NH_;  }
    else if (bt < 20) { Wsel = Wk; Csel = Kp + (size_t)z * KPSZ; nrow0 = (bt - 16) * 128; heads = NKV_; }
    else              { Wsel = Wv; Csel = Vp + (size_t)z * KPSZ; nrow0 = (bt - 20) * 128; heads = NKV_; }

    const int srow = 32 * wave + (lane >> 2);
    // inverse-swizzled global source chunk (T2 both-sides)
    const int scol = (((lane & 3) ^ ((lane >> 3) & 3))) * 8;
    const _Float16* Ag = A    + (size_t)(bm + srow)    * HID_ + kbase + scol;
    const _Float16* Wg = Wsel + (size_t)(nrow0 + srow) * HID_ + kbase + scol;

    // wave-uniform staging bases; HW adds lane*16B (linear dest)
    const unsigned aoff = (unsigned)(wave * 2048);

    f32x4 acc[4][4];
    const f32x4 fz = {0.f, 0.f, 0.f, 0.f};
#pragma unroll
    for (int i = 0; i < 4; i++)
#pragma unroll
        for (int j = 0; j < 4; j++) acc[i][j] = fz;

    const int ml = lane & 15, kg = lane >> 4;
    const int kgx = kg ^ ((ml >> 1) & 3);   // swizzled read chunk (per-lane const)

#define QKV_STAGE(d, k0) do {                                                 \
        _Float16* la_ = (_Float16*)(smem + (d) * 16384 + aoff);               \
        _Float16* lw_ = (_Float16*)(smem + (d) * 16384 + 8192 + aoff);        \
        async_copy16(Ag + (k0), la_);                                         \
        async_copy16(Ag + (k0) + (size_t)16 * HID_, la_ + 16 * 32);           \
        async_copy16(Wg + (k0), lw_);                                         \
        async_copy16(Wg + (k0) + (size_t)16 * HID_, lw_ + 16 * 32);           \
    } while (0)

#define QKV_COMPUTE(d) do {                                                   \
        const _Float16* tA = (const _Float16*)(smem + (d) * 16384);           \
        const _Float16* tW = (const _Float16*)(smem + (d) * 16384 + 8192);    \
        f16x8 a[4], b[4];                                                     \
        _Pragma("unroll")                                                     \
        for (int mi = 0; mi < 4; mi++)                                        \
            a[mi] = *(const f16x8*)&tA[(wr + mi * 16 + ml) * 32 + kgx * 8];   \
        _Pragma("unroll")                                                     \
        for (int ni = 0; ni < 4; ni++)                                        \
            b[ni] = *(const f16x8*)&tW[(wc + ni * 16 + ml) * 32 + kgx * 8];   \
        _Pragma("unroll")                                                     \
        for (int mi = 0; mi < 4; mi++)                                        \
            _Pragma("unroll")                                                 \
            for (int ni = 0; ni < 4; ni++)                                    \
                acc[mi][ni] = __builtin_amdgcn_mfma_f32_16x16x32_f16(         \
                    a[mi], b[ni], acc[mi][ni], 0, 0, 0);                      \
    } while (0)

    QKV_STAGE(0, 0);
    int cbuf = 0;
    for (int t = 0; t < 31; t++) {
        int nbuf = (cbuf == 2) ? 0 : cbuf + 1;
        QKV_STAGE(nbuf, (t + 1) * 32);    // 4 loads issued, stay in flight
        // retire only the 4 OLDEST loads (= buffer cbuf, staged last iter)
        asm volatile("s_waitcnt vmcnt(4)" ::: "memory");
        __builtin_amdgcn_s_barrier();
        __builtin_amdgcn_sched_barrier(0);

        QKV_COMPUTE(cbuf);                // no trailing barrier (3-buf safety)
        cbuf = nbuf;
    }
    // peeled last tile
    asm volatile("s_waitcnt vmcnt(0)" ::: "memory");
    __builtin_amdgcn_s_barrier();
    __builtin_amdgcn_sched_barrier(0);
    QKV_COMPUTE(cbuf);
#undef QKV_STAGE
#undef QKV_COMPUTE

#pragma unroll
    for (int mi = 0; mi < 4; mi++) {
#pragma unroll
        for (int ni = 0; ni < 4; ni++) {
#pragma unroll
            for (int r = 0; r < 4; r++) {
                int m = bm + wr + mi * 16 + kg * 4 + r;
                int n = nrow0 + wc + ni * 16 + ml;
                int hh = n >> 7, d2 = n & 127;
                int b_ = m >> 10, s = m & 1023;
                size_t idx = (((size_t)(b_ * heads + hh)) * S_ + s) * HD_ + d2;
                Csel[idx] = (_Float16)acc[mi][ni][r];
            }
        }
    }
}

// ---------------------------------------------------------------------------
// Output GEMM, in-block split-K=2, 512 threads, grid (16,16) = 1 block/CU.
// Triple-buffer, one barrier per K-step; counted vmcnt(4); T2 swizzle.
// ---------------------------------------------------------------------------
__global__ __launch_bounds__(512) void out_gemm(
    const _Float16* __restrict__ A,
    const _Float16* __restrict__ W,
    float* __restrict__ Cout)
{
    // 3 buffers: buf d at d*32768; A(kh) at +kh*8192, W(kh) at +16384+kh*8192
    __shared__ __align__(16) unsigned char smem[98304];

    const int tid  = threadIdx.x;
    const int lane = tid & 63, wave = tid >> 6;
    const int kh = wave >> 2;               // K-half this wave owns
    const int wv = wave & 3;                // tile-wave within half
    const int wr = (wv >> 1) * 64, wc = (wv & 1) * 64;
    const int bm = blockIdx.y * 128, bn = blockIdx.x * 128;
    const int kbase = kh * (HID_ / 2);

    const int srow = 32 * wv + (lane >> 2);
    const int scol = (((lane & 3) ^ ((lane >> 3) & 3))) * 8;   // inverse-swz src
    const _Float16* Ag = A + (size_t)(bm + srow) * HID_ + kbase + scol;
    const _Float16* Wg = W + (size_t)(bn + srow) * HID_ + kbase + scol;

    const unsigned aoff = (unsigned)(kh * 8192 + 32 * wv * 64);
    const unsigned woff = (unsigned)(16384 + kh * 8192 + 32 * wv * 64);

    f32x4 acc[4][4];
    const f32x4 fz = {0.f, 0.f, 0.f, 0.f};
#pragma unroll
    for (int i = 0; i < 4; i++)
#pragma unroll
        for (int j = 0; j < 4; j++) acc[i][j] = fz;

    const int ml = lane & 15, kg = lane >> 4;
    const int kgx = kg ^ ((ml >> 1) & 3);   // swizzled read chunk

#define OG_STAGE(d, k0) do {                                                  \
        _Float16* la_ = (_Float16*)(smem + (d) * 32768 + aoff);               \
        _Float16* lw_ = (_Float16*)(smem + (d) * 32768 + woff);               \
        async_copy16(Ag + (k0), la_);                                         \
        async_copy16(Ag + (k0) + (size_t)16 * HID_, la_ + 16 * 32);           \
        async_copy16(Wg + (k0), lw_);                                         \
        async_copy16(Wg + (k0) + (size_t)16 * HID_, lw_ + 16 * 32);           \
    } while (0)

#define OG_COMPUTE(d) do {                                                    \
        const _Float16* tA = (const _Float16*)(smem + (d) * 32768 + kh * 8192);\
        const _Float16* tW = (const _Float16*)(smem + (d) * 32768 + 16384 + kh * 8192);\
        f16x8 a[4], b[4];                                                     \
        _Pragma("unroll")                                                     \
        for (int mi = 0; mi < 4; mi++)                                        \
            a[mi] = *(const f16x8*)&tA[(wr + mi * 16 + ml) * 32 + kgx * 8];   \
        _Pragma("unroll")                                                     \
        for (int ni = 0; ni < 4; ni++)                                        \
            b[ni] = *(const f16x8*)&tW[(wc + ni * 16 + ml) * 32 + kgx * 8];   \
        _Pragma("unroll")                                                     \
        for (int mi = 0; mi < 4; mi++)                                        \
            _Pragma("unroll")                                                 \
            for (int ni = 0; ni < 4; ni++)                                    \
                acc[mi][ni] = __builtin_amdgcn_mfma_f32_16x16x32_f16(         \
                    a[mi], b[ni], acc[mi][ni], 0, 0, 0);                      \
    } while (0)

    OG_STAGE(0, 0);
    int cbuf = 0;
    for (int t = 0; t < 31; t++) {
        int nbuf = (cbuf == 2) ? 0 : cbuf + 1;
        OG_STAGE(nbuf, (t + 1) * 32);    // 4 loads issued, stay in flight
        asm volatile("s_waitcnt vmcnt(4)" ::: "memory");
        __builtin_amdgcn_s_barrier();
        __builtin_amdgcn_sched_barrier(0);

        OG_COMPUTE(cbuf);                // no trailing barrier (3-buf safety)
        cbuf = nbuf;
    }
    asm volatile("s_waitcnt vmcnt(0)" ::: "memory");
    __builtin_amdgcn_s_barrier();
    __builtin_amdgcn_sched_barrier(0);
    OG_COMPUTE(cbuf);
#undef OG_STAGE
#undef OG_COMPUTE

    // cross-half reduce through LDS (aliases staging; stride 65 floats keeps
    // scalar f32 accesses conflict-free on the 32 banks)
    __syncthreads();                     // full drain before aliasing smem
    float* red = (float*)smem;
    float* rp  = red + ((size_t)(wv * 64 + lane)) * 65;
    if (kh == 1) {
#pragma unroll
        for (int mi = 0; mi < 4; mi++)
#pragma unroll
            for (int ni = 0; ni < 4; ni++)
#pragma unroll
                for (int r = 0; r < 4; r++)
                    rp[mi * 16 + ni * 4 + r] = acc[mi][ni][r];
    }
    __syncthreads();
    if (kh == 0) {
#pragma unroll
        for (int mi = 0; mi < 4; mi++)
#pragma unroll
            for (int ni = 0; ni < 4; ni++)
#pragma unroll
                for (int r = 0; r < 4; r++) {
                    float v = acc[mi][ni][r] + rp[mi * 16 + ni * 4 + r];
                    int m = bm + wr + mi * 16 + kg * 4 + r;
                    int n = bn + wc + ni * 16 + ml;
                    Cout[(size_t)m * HID_ + n] = v;
                }
    }
}

// ---------------------------------------------------------------------------
// rope kernel: K (partial-reduce + rope + rms) + V (partial-reduce + cast).
// Rows: [0,8192) K, [8192,16384) V. (Q fused into stick_attn.)
// ---------------------------------------------------------------------------
__global__ __launch_bounds__(256) void rope_k_v(
    const _Float16* __restrict__ Kp, const _Float16* __restrict__ Vp,
    const float* __restrict__ kw,
    _Float16* __restrict__ Kout, _Float16* __restrict__ Vout)
{
    int row = blockIdx.x * 4 + (threadIdx.x >> 6);
    int lane = threadIdx.x & 63;

    if (row >= 8192) {   // V: partial-sum + cast
        int lrow = row - 8192;
        size_t off = (size_t)lrow * HD_ + lane * 2;
        float a0 = 0.f, a1 = 0.f;
#pragma unroll
        for (int zp = 0; zp < NZ_; zp++) {
            a0 += (float)Vp[(size_t)zp * KPSZ + off];
            a1 += (float)Vp[(size_t)zp * KPSZ + off + 1];
        }
        _Float16* q = Vout + (size_t)lrow * HD_;
        q[lane * 2]     = (_Float16)a0;
        q[lane * 2 + 1] = (_Float16)a1;
        return;
    }

    // K: partial-reduce + rope + rms
    _Float16* q = Kout + (size_t)row * HD_;
    int s = row & (S_ - 1);
    size_t base = (size_t)row * HD_;
    float x1 = 0.f, x2 = 0.f;
#pragma unroll
    for (int zp = 0; zp < NZ_; zp++) {
        x1 += (float)Kp[(size_t)zp * KPSZ + base + lane];
        x2 += (float)Kp[(size_t)zp * KPSZ + base + lane + 64];
    }

    float invf = __builtin_amdgcn_exp2f(-(float)lane * 0.2076205059304601f);
    float ang = (float)s * invf;
    float sn = __sinf(ang);
    float c  = __cosf(ang);

    float y1 = x1 * c - x2 * sn;
    float y2 = x1 * sn + x2 * c;

    float ss = y1 * y1 + y2 * y2;
#pragma unroll
    for (int off = 32; off > 0; off >>= 1) ss += __shfl_xor(ss, off);

    float scl = rsqrtf(ss * (1.0f / 128.0f) + 1e-6f);
    q[lane]      = (_Float16)(y1 * scl * kw[lane]);
    q[lane + 64] = (_Float16)(y2 * scl * kw[lane + 64]);
}

// ---------------------------------------------------------------------------
// MFMA stick-breaking attention with K/V register prefetch.
// Q path fused: reads both Qp split-K partials, applies RoPE + RMSNorm while
// the first K/V prefetch is in flight, writes Qs.
// R12: T1 XCD-chunked slot swizzle — slot bits rotated so each XCD's
// round-robin share covers ONE (b,kvh) K/V working set (512KB, fits L2)
// instead of all 8 (4MB). Bijective on [0,256); the heavy/light qb pairing
// is positional (pos s and s+256 still complementary), so balance holds.
// BQ=BK=64, 512 threads (8 waves). T5 setprio around MFMA clusters.
// ---------------------------------------------------------------------------
#define QK_STR 136
#define VT_STR 72
#define SS_STR 68
#define AT_STR 72

__global__ __launch_bounds__(512) void stick_attn(
    const _Float16* __restrict__ Qp,   // 2 x QPSZ pre-rope partials
    const _Float16* __restrict__ K,
    const _Float16* __restrict__ V,
    const float* __restrict__ qwgt,
    _Float16* __restrict__ AO)
{
    __shared__ __align__(16) _Float16 Qs[64][QK_STR];
    __shared__ __align__(16) _Float16 Ks[64][QK_STR];
    __shared__ __align__(16) _Float16 Vt[128][VT_STR];
    __shared__ __align__(16) float    Ss[64][SS_STR];
    __shared__ __align__(16) _Float16 atts[64][AT_STR];
    __shared__ float paccs[64];

    const int bid = blockIdx.x;
    const int slot0 = bid & 255, phase = bid >> 8;
    // T1 XCD-chunk: rotate slot bits (bijective); XCD n covers slots 32n..32n+31
    const int slot = ((slot0 & 7) << 5) | (slot0 >> 3);
    const int hb = slot >> 3, iw = slot & 7;
    const int b = hb >> 4, h = hb & 15;
    const int qb = phase ? iw : 15 - iw;

    const int kvh = h / GROUPS;
    const int tid = threadIdx.x;
    const int lane = tid & 63, wave = tid >> 6;
    const int qw = wave >> 1;
    const int kh = wave & 1;
    const int ml = lane & 15, quad = lane >> 4;

    const _Float16* Kbase = K + ((size_t)(b * NKV_ + kvh) * S_) * HD_;
    const _Float16* Vbase = V + ((size_t)(b * NKV_ + kvh) * S_) * HD_;

    const f32x4 fz = {0.f, 0.f, 0.f, 0.f};

    const int qi0 = qb * 64;

    // K staging geometry: thread loads rows kr, kr+32 at col kc (8 f16)
    const int kr = tid >> 4, kc = (tid & 15) * 8;
    // V staging geometry: thread loads key=lane, d-range wave*16 .. +16
    const _Float16* Vrow = Vbase + (size_t)lane * HD_ + wave * 16;

    // prefetch first tile (kb = qb) — issued BEFORE Q-rope so the HBM
    // latency hides under the rope VALU work below
    f16x8 kA, kB, vA, vB;
    {
        const _Float16* kp = Kbase + (size_t)(qb * 64 + kr) * HD_ + kc;
        kA = *(const f16x8*)(kp);
        kB = *(const f16x8*)(kp + (size_t)32 * HD_);
        const _Float16* vp = Vrow + (size_t)(qb * 64) * HD_;
        vA = *(const f16x8*)(vp);
        vB = *(const f16x8*)(vp + 8);
    }

    // fused Q: split-K reduce + RoPE + RMSNorm -> Qs (8 rows per wave)
    {
        float invf = __builtin_amdgcn_exp2f(-(float)lane * 0.2076205059304601f);
        float w1 = qwgt[lane], w2 = qwgt[lane + 64];
        size_t qbase = ((size_t)(b * NH_ + h) * S_ + qi0 + wave * 8) * HD_;
#pragma unroll
        for (int r8 = 0; r8 < 8; r8++) {
            int row = wave * 8 + r8;
            size_t base = qbase + (size_t)r8 * HD_;
            float x1 = (float)Qp[base + lane]
                     + (float)Qp[QPSZ + base + lane];
            float x2 = (float)Qp[base + lane + 64]
                     + (float)Qp[QPSZ + base + lane + 64];
            float ang = (float)(qi0 + row) * invf;
            float sn = __sinf(ang);
            float c  = __cosf(ang);
            float y1 = x1 * c - x2 * sn;
            float y2 = x1 * sn + x2 * c;
            float ss = y1 * y1 + y2 * y2;
#pragma unroll
            for (int off = 32; off > 0; off >>= 1) ss += __shfl_xor(ss, off);
            float scl = rsqrtf(ss * (1.0f / 128.0f) + 1e-6f);
            Qs[row][lane]      = (_Float16)(y1 * scl * w1);
            Qs[row][lane + 64] = (_Float16)(y2 * scl * w2);
        }
    }
    if (tid < 64) paccs[tid] = 1.f;
    __syncthreads();

    f16x8 aq[4];
#pragma unroll
    for (int ks = 0; ks < 4; ks++)
        aq[ks] = *(const f16x8*)&Qs[qw * 16 + ml][ks * 32 + quad * 8];

    f32x4 accO[4] = {fz, fz, fz, fz};

    for (int kb = qb; kb >= 0; --kb) {
        __syncthreads();   // prev PV/scan reads of Ks/Vt/Ss/atts done

        // stage prefetched K from registers (b128 writes)
        *(f16x8*)&Ks[kr][kc]      = kA;
        *(f16x8*)&Ks[kr + 32][kc] = kB;

        // stage prefetched V transposed: DPP pair-exchange + packed b32 writes
        {
            int4 i0 = *(int4*)&vA, i1 = *(int4*)&vB;
            int4 p0, p1;
            p0.x = dpp_swap1(i0.x); p0.y = dpp_swap1(i0.y);
            p0.z = dpp_swap1(i0.z); p0.w = dpp_swap1(i0.w);
            p1.x = dpp_swap1(i1.x); p1.y = dpp_swap1(i1.y);
            p1.z = dpp_swap1(i1.z); p1.w = dpp_swap1(i1.w);
            bool ev = !(lane & 1);
            int4 al = ev ? i0 : p1;   // low halves: key 2k
            int4 bh = ev ? p0 : i1;   // high halves: key 2k+1
            int r0w = wave * 16 + (ev ? 0 : 8);
            int colk = lane & ~1;
            int ac[4] = {al.x, al.y, al.z, al.w};
            int bc[4] = {bh.x, bh.y, bh.z, bh.w};
#pragma unroll
            for (int i = 0; i < 8; i++) {
                int c = i >> 1;
                unsigned pack = (i & 1)
                    ? (((unsigned)ac[c] >> 16) | ((unsigned)bc[c] & 0xffff0000u))
                    : (((unsigned)ac[c] & 0xffffu) | ((unsigned)bc[c] << 16));
                *(unsigned*)&Vt[r0w + i][colk] = pack;
            }
        }
        __syncthreads();

        // issue prefetch for next tile — consumed at next staging phase,
        // covered by the QK+scan+PV compute below
        if (kb > 0) {
            const _Float16* kp = Kbase + (size_t)((kb - 1) * 64 + kr) * HD_ + kc;
            kA = *(const f16x8*)(kp);
            kB = *(const f16x8*)(kp + (size_t)32 * HD_);
            const _Float16* vp = Vrow + (size_t)((kb - 1) * 64) * HD_;
            vA = *(const f16x8*)(vp);
            vB = *(const f16x8*)(vp + 8);
        }

        // QK^T -> Ss (scaled)
        f32x4 accS[2] = {fz, fz};
        __builtin_amdgcn_s_setprio(1);
#pragma unroll
        for (int ks = 0; ks < 4; ks++) {
#pragma unroll
            for (int ni = 0; ni < 2; ni++) {
                f16x8 bf = *(const f16x8*)
                    &Ks[kh * 32 + ni * 16 + ml][ks * 32 + quad * 8];
                accS[ni] = __builtin_amdgcn_mfma_f32_16x16x32_f16(
                    aq[ks], bf, accS[ni], 0, 0, 0);
            }
        }
        __builtin_amdgcn_s_setprio(0);
#pragma unroll
        for (int ni = 0; ni < 2; ni++)
#pragma unroll
            for (int r = 0; r < 4; r++)
                Ss[qw * 16 + quad * 4 + r][kh * 32 + ni * 16 + ml] =
                    accS[ni][r] * SCALE_;
        __syncthreads();

        // sigmoid-domain scan: om = sig(-L) exact, s = 1-om, suffix products
        {
            int q = tid >> 3, seg = tid & 7;
            int qg = qi0 + q;
            int j0 = kb * 64 + seg * 8;
            float4 s0 = *(float4*)&Ss[q][seg * 8];
            float4 s1 = *(float4*)&Ss[q][seg * 8 + 4];
            float L[8] = {s0.x, s0.y, s0.z, s0.w, s1.x, s1.y, s1.z, s1.w};
            float sv[8], om[8];
#pragma unroll
            for (int i = 0; i < 8; i++) {
                float u = __expf(L[i]);
                float o = __builtin_amdgcn_rcpf(1.f + u);
                bool valid = (j0 + i < qg);
                om[i] = valid ? o : 1.f;
                sv[i] = valid ? (1.f - o) : 0.f;
            }
            float suf = 1.f, lo[8];
#pragma unroll
            for (int i = 7; i >= 0; --i) {
                lo[i] = suf; suf *= om[i];
            }
            float x = suf;
#pragma unroll
            for (int off = 1; off < 8; off <<= 1) {
                float y = __shfl_down(x, off);
                if (seg + off < 8) x *= y;
            }
            float bx = __shfl_down(x, 1);
            float base = (seg == 7) ? 1.f : bx;
            float paccq = paccs[q];
            float pb = base * paccq;
            f16x8 av;
#pragma unroll
            for (int i = 0; i < 8; i++)
                av[i] = (_Float16)(sv[i] * lo[i] * pb);
            *(f16x8*)&atts[q][seg * 8] = av;
            if (seg == 0) paccs[q] = paccq * x;
        }
        __syncthreads();

        // PV
        __builtin_amdgcn_s_setprio(1);
#pragma unroll
        for (int ks = 0; ks < 2; ks++) {
            f16x8 ap = *(const f16x8*)&atts[qw * 16 + ml][ks * 32 + quad * 8];
#pragma unroll
            for (int ni = 0; ni < 4; ni++) {
                f16x8 bv = *(const f16x8*)
                    &Vt[kh * 64 + ni * 16 + ml][ks * 32 + quad * 8];
                accO[ni] = __builtin_amdgcn_mfma_f32_16x16x32_f16(
                    ap, bv, accO[ni], 0, 0, 0);
            }
        }
        __builtin_amdgcn_s_setprio(0);
    }

#pragma unroll
    for (int ni = 0; ni < 4; ni++) {
#pragma unroll
        for (int r = 0; r < 4; r++) {
            int qg = qi0 + qw * 16 + quad * 4 + r;
            int d = kh * 64 + ni * 16 + ml;
            AO[((size_t)(b * S_ + qg) * NH_ + h) * HD_ + d] =
                (_Float16)accO[ni][r];
        }
    }
}

// ---------------------------------------------------------------------------
extern "C" void kernel_launch(void* const* d_in, const int* in_sizes, int n_in,
                              void* d_out, int out_size, void* d_ws, size_t ws_size,
                              hipStream_t stream)
{
    const float* hs = (const float*)d_in[0];
    const float* Wq = (const float*)d_in[1];
    const float* Wk = (const float*)d_in[2];
    const float* Wv = (const float*)d_in[3];
    const float* Wo = (const float*)d_in[4];
    const float* qw = (const float*)d_in[5];
    const float* kw = (const float*)d_in[6];
    float* out = (float*)d_out;

    // f16 workspace layout (split-K=2 partials)
    _Float16* Qp  = (_Float16*)d_ws;         // 2 x QPSZ
    _Float16* Kp  = Qp + (size_t)NZ_ * QPSZ; // 2 x KPSZ
    _Float16* Vp  = Kp + (size_t)NZ_ * KPSZ; // 2 x KPSZ
    _Float16* hsh = Vp + (size_t)NZ_ * KPSZ;
    _Float16* Wqh = hsh + 4194304;
    _Float16* Wkh = Wqh + 4194304;
    _Float16* Wvh = Wkh + 1048576;
    _Float16* Woh = Wvh + 1048576;       // 4,194,304
    _Float16* Kh  = Woh + 4194304;       // post-rope K
    _Float16* Vh  = Kh + 1048576;        // V
    // stream-ordered alias
    _Float16* AOh = hsh;   // attention out, after qkv consumed hs

    dim3 blk(256);

    // one launch: cast hs | Wq | Wk | Wv | Wo to f16
    cast5_f16<<<14336, blk, 0, stream>>>(
        (const float4*)hs, (ushort4*)hsh, 1048576,
        (const float4*)Wq, (ushort4*)Wqh, 1048576,
        (const float4*)Wk, (ushort4*)Wkh, 262144,
        (const float4*)Wv, (ushort4*)Wvh, 262144,
        (const float4*)Wo, (ushort4*)Woh, 1048576);

    // fused QKV projection, split-K=2, triple-buffer 1-barrier pipeline
    qkv_gemm<<<dim3(24, 16, NZ_), blk, 0, stream>>>(hsh, Wqh, Wkh, Wvh,
                                                    Qp, Kp, Vp);

    // K rope+rms + V reduce (Q handled inside stick_attn)
    rope_k_v<<<dim3(16384 / 4), blk, 0, stream>>>(Kp, Vp, kw, Kh, Vh);

    // stick-breaking attention (fused Q reduce+rope+rms) -> f16 (b,s,h,d)
    stick_attn<<<dim3(512), dim3(512), 0, stream>>>(Qp, Kh, Vh, qw, AOh);

    // output projection, triple-buffer 1-barrier pipeline -> f32 out
    out_gemm<<<dim3(16, 16), dim3(512), 0, stream>>>(AOh, Woh, out);
}